// Round 1
// baseline (1414.571 us; speedup 1.0000x reference)
//
#include <hip/hip_runtime.h>
#include <math.h>

#define C_DIM 512
#define T_DIM 2048
#define B_DIM 8

#define BM 64
#define BN 64
#define BK 16
#define TM 4
#define TN 4
#define PAD 4   // +4 keeps LDS rows 16B-aligned (vector ops OK) and breaks conflicts

// -----------------------------------------------------------------------------
// conv1x1: Out[b][m][n] = relu( sum_k W[m][k] * X[b][k][n] + bias[m] ) (+resid)
// W row-major [C,C] (K contiguous), X [B,C,T] (N contiguous)  -> "NN" GEMM
// -----------------------------------------------------------------------------
__global__ __launch_bounds__(256) void conv_kernel(
    const float* __restrict__ W, const float* __restrict__ bias,
    const float* __restrict__ X, float* __restrict__ Out,
    const float* __restrict__ resid)
{
    __shared__ float As[BK][BM + PAD];   // [k][m]
    __shared__ float Bs[BK][BN + PAD];   // [k][n]

    const int b  = blockIdx.z;
    const int m0 = blockIdx.y * BM;
    const int n0 = blockIdx.x * BN;
    const float* Xb = X + (size_t)b * C_DIM * T_DIM;

    const int tid = threadIdx.x;
    const int tx = tid & 15, ty = tid >> 4;

    float acc[TM][TN] = {};

    for (int k0 = 0; k0 < C_DIM; k0 += BK) {
        // A tile: W[m0+r][k0+kq .. +3]  -> transpose-store into As[k][m]
        {
            const int r = tid >> 2, kq = (tid & 3) << 2;
            const float4 v = *(const float4*)(W + (size_t)(m0 + r) * C_DIM + k0 + kq);
            As[kq + 0][r] = v.x; As[kq + 1][r] = v.y;
            As[kq + 2][r] = v.z; As[kq + 3][r] = v.w;
        }
        // B tile: X[k0+kk][n0+nq .. +3]
        {
            const int kk = tid >> 4, nq = (tid & 15) << 2;
            *(float4*)&Bs[kk][nq] = *(const float4*)(Xb + (size_t)(k0 + kk) * T_DIM + n0 + nq);
        }
        __syncthreads();
        #pragma unroll
        for (int k = 0; k < BK; ++k) {
            float a[TM], bv[TN];
            #pragma unroll
            for (int i = 0; i < TM; ++i) a[i] = As[k][ty * TM + i];
            #pragma unroll
            for (int j = 0; j < TN; ++j) bv[j] = Bs[k][tx * TN + j];
            #pragma unroll
            for (int i = 0; i < TM; ++i)
                #pragma unroll
                for (int j = 0; j < TN; ++j)
                    acc[i][j] += a[i] * bv[j];
        }
        __syncthreads();
    }

    float* Ob = Out + (size_t)b * C_DIM * T_DIM;
    const float* Rb = resid ? resid + (size_t)b * C_DIM * T_DIM : nullptr;
    #pragma unroll
    for (int i = 0; i < TM; ++i) {
        const int m = m0 + ty * TM + i;
        const float bb = bias[m];
        #pragma unroll
        for (int j = 0; j < TN; ++j) {
            const int n = n0 + tx * TN + j;
            float v = acc[i][j] + bb;
            v = v > 0.f ? v : 0.f;
            if (Rb) v += Rb[(size_t)m * T_DIM + n];
            Ob[(size_t)m * T_DIM + n] = v;
        }
    }
}

// -----------------------------------------------------------------------------
// scores[b][i][j] = sum_c theta[b][c][i] * phi[b][c][j]
// Both operands are K-major in memory with contiguous M/N -> "TN" GEMM (nicest).
// -----------------------------------------------------------------------------
__global__ __launch_bounds__(256) void scores_kernel(
    const float* __restrict__ Th, const float* __restrict__ Ph,
    float* __restrict__ S)
{
    __shared__ float As[BK][BM + PAD];   // [c][i]
    __shared__ float Bs[BK][BN + PAD];   // [c][j]

    const int b  = blockIdx.z;
    const int m0 = blockIdx.y * BM;   // i
    const int n0 = blockIdx.x * BN;   // j
    const float* A  = Th + (size_t)b * C_DIM * T_DIM;
    const float* Bp = Ph + (size_t)b * C_DIM * T_DIM;

    const int tid = threadIdx.x;
    const int tx = tid & 15, ty = tid >> 4;

    float acc[TM][TN] = {};

    for (int k0 = 0; k0 < C_DIM; k0 += BK) {
        const int kk = tid >> 4, q = (tid & 15) << 2;
        *(float4*)&As[kk][q] = *(const float4*)(A  + (size_t)(k0 + kk) * T_DIM + m0 + q);
        *(float4*)&Bs[kk][q] = *(const float4*)(Bp + (size_t)(k0 + kk) * T_DIM + n0 + q);
        __syncthreads();
        #pragma unroll
        for (int k = 0; k < BK; ++k) {
            float a[TM], bv[TN];
            #pragma unroll
            for (int i = 0; i < TM; ++i) a[i] = As[k][ty * TM + i];
            #pragma unroll
            for (int j = 0; j < TN; ++j) bv[j] = Bs[k][tx * TN + j];
            #pragma unroll
            for (int i = 0; i < TM; ++i)
                #pragma unroll
                for (int j = 0; j < TN; ++j)
                    acc[i][j] += a[i] * bv[j];
        }
        __syncthreads();
    }

    float* Sb = S + (size_t)b * T_DIM * T_DIM;
    #pragma unroll
    for (int i = 0; i < TM; ++i) {
        const int m = m0 + ty * TM + i;
        #pragma unroll
        for (int j = 0; j < TN; ++j)
            Sb[(size_t)m * T_DIM + n0 + tx * TN + j] = acc[i][j];
    }
}

// -----------------------------------------------------------------------------
// softmax over last dim, in place. One 256-thread block per row (T=2048 cols).
// -----------------------------------------------------------------------------
__global__ __launch_bounds__(256) void softmax_kernel(float* __restrict__ S)
{
    float* p = S + (size_t)blockIdx.x * T_DIM;
    const int tid = threadIdx.x;

    float v[8];
    float lmax = -INFINITY;
    #pragma unroll
    for (int c = 0; c < 8; ++c) {
        v[c] = p[tid + c * 256];
        lmax = fmaxf(lmax, v[c]);
    }
    #pragma unroll
    for (int off = 32; off; off >>= 1)
        lmax = fmaxf(lmax, __shfl_down(lmax, off, 64));
    __shared__ float redm[4];
    if ((tid & 63) == 0) redm[tid >> 6] = lmax;
    __syncthreads();
    const float m = fmaxf(fmaxf(redm[0], redm[1]), fmaxf(redm[2], redm[3]));

    float lsum = 0.f;
    #pragma unroll
    for (int c = 0; c < 8; ++c) {
        v[c] = __expf(v[c] - m);
        lsum += v[c];
    }
    #pragma unroll
    for (int off = 32; off; off >>= 1)
        lsum += __shfl_down(lsum, off, 64);
    __shared__ float reds[4];
    if ((tid & 63) == 0) reds[tid >> 6] = lsum;
    __syncthreads();
    const float inv = 1.f / (reds[0] + reds[1] + reds[2] + reds[3]);

    #pragma unroll
    for (int c = 0; c < 8; ++c)
        p[tid + c * 256] = v[c] * inv;
}

// -----------------------------------------------------------------------------
// feature[b][c][i] = sum_j G[b][c][j] * Attn[b][i][j]   ("NT" GEMM)
// M=C (c), N=T (i), K=T (j). Both operands K-contiguous -> transpose-store B.
// -----------------------------------------------------------------------------
__global__ __launch_bounds__(256) void feature_kernel(
    const float* __restrict__ G, const float* __restrict__ Attn,
    float* __restrict__ F)
{
    __shared__ float As[BK][BM + PAD];   // [j][c]
    __shared__ float Bs[BK][BN + PAD];   // [j][i]

    const int b  = blockIdx.z;
    const int m0 = blockIdx.y * BM;   // c
    const int n0 = blockIdx.x * BN;   // i
    const float* Gb = G    + (size_t)b * C_DIM * T_DIM;
    const float* Ab = Attn + (size_t)b * T_DIM * T_DIM;

    const int tid = threadIdx.x;
    const int tx = tid & 15, ty = tid >> 4;

    float acc[TM][TN] = {};

    for (int k0 = 0; k0 < T_DIM; k0 += BK) {
        const int r = tid >> 2, kq = (tid & 3) << 2;
        {   // A tile: G[m0+r][k0+kq..+3] -> As[k][m]
            const float4 v = *(const float4*)(Gb + (size_t)(m0 + r) * T_DIM + k0 + kq);
            As[kq + 0][r] = v.x; As[kq + 1][r] = v.y;
            As[kq + 2][r] = v.z; As[kq + 3][r] = v.w;
        }
        {   // B tile: Attn[n0+r][k0+kq..+3] -> Bs[k][n]
            const float4 v = *(const float4*)(Ab + (size_t)(n0 + r) * T_DIM + k0 + kq);
            Bs[kq + 0][r] = v.x; Bs[kq + 1][r] = v.y;
            Bs[kq + 2][r] = v.z; Bs[kq + 3][r] = v.w;
        }
        __syncthreads();
        #pragma unroll
        for (int k = 0; k < BK; ++k) {
            float a[TM], bv[TN];
            #pragma unroll
            for (int i = 0; i < TM; ++i) a[i] = As[k][ty * TM + i];
            #pragma unroll
            for (int j = 0; j < TN; ++j) bv[j] = Bs[k][tx * TN + j];
            #pragma unroll
            for (int i = 0; i < TM; ++i)
                #pragma unroll
                for (int j = 0; j < TN; ++j)
                    acc[i][j] += a[i] * bv[j];
        }
        __syncthreads();
    }

    float* Fb = F + (size_t)b * C_DIM * T_DIM;
    #pragma unroll
    for (int i = 0; i < TM; ++i) {
        const int m = m0 + ty * TM + i;
        #pragma unroll
        for (int j = 0; j < TN; ++j)
            Fb[(size_t)m * T_DIM + n0 + tx * TN + j] = acc[i][j];
    }
}

// -----------------------------------------------------------------------------
extern "C" void kernel_launch(void* const* d_in, const int* in_sizes, int n_in,
                              void* d_out, int out_size, void* d_ws, size_t ws_size,
                              hipStream_t stream)
{
    const float* x       = (const float*)d_in[0];
    const float* w_theta = (const float*)d_in[1];
    const float* b_theta = (const float*)d_in[2];
    const float* w_phi   = (const float*)d_in[3];
    const float* b_phi   = (const float*)d_in[4];
    const float* w_g     = (const float*)d_in[5];
    const float* b_g     = (const float*)d_in[6];
    const float* w_w     = (const float*)d_in[7];
    const float* b_w     = (const float*)d_in[8];
    float* out = (float*)d_out;

    const size_t feat_elems = (size_t)B_DIM * C_DIM * T_DIM;   // 8.4M floats
    float* ws      = (float*)d_ws;
    float* theta   = ws;
    float* phi     = theta + feat_elems;
    float* g       = phi + feat_elems;
    float* scores  = g + feat_elems;                           // 33.6M floats
    float* feature = theta;                                    // theta dead after scores

    const dim3 blk(256);
    const dim3 gconv(T_DIM / BN, C_DIM / BM, B_DIM);
    const dim3 gsc  (T_DIM / BN, T_DIM / BM, B_DIM);

    conv_kernel<<<gconv, blk, 0, stream>>>(w_theta, b_theta, x, theta, nullptr);
    conv_kernel<<<gconv, blk, 0, stream>>>(w_phi,   b_phi,   x, phi,   nullptr);
    conv_kernel<<<gconv, blk, 0, stream>>>(w_g,     b_g,     x, g,     nullptr);
    scores_kernel<<<gsc, blk, 0, stream>>>(theta, phi, scores);
    softmax_kernel<<<dim3(B_DIM * T_DIM), blk, 0, stream>>>(scores);
    feature_kernel<<<gconv, blk, 0, stream>>>(g, scores, feature);
    conv_kernel<<<gconv, blk, 0, stream>>>(w_w, b_w, feature, out, x);
}

// Round 2
// 319.108 us; speedup vs baseline: 4.4329x; 4.4329x over previous
//
#include <hip/hip_runtime.h>
#include <math.h>

#define C_DIM 512
#define T_DIM 2048
#define B_DIM 8

typedef _Float16 f16;
typedef __attribute__((ext_vector_type(8))) _Float16 half8;
typedef __attribute__((ext_vector_type(4))) _Float16 half4;
typedef __attribute__((ext_vector_type(4))) float floatx4;

// LDS row stride in halves: 32 data + 8 pad = 40 (20 words) -> max 2-way bank
// conflict on ds_read_b128 (free per m136); 16B alignment preserved (80 B rows).
#define LDSK 40

// ---------------------------------------------------------------------------
// fp32 [512][512] weights -> fp16, same layout. z selects which weight.
// ---------------------------------------------------------------------------
__global__ __launch_bounds__(256) void convert_w_kernel(
    const float* __restrict__ w0, const float* __restrict__ w1,
    const float* __restrict__ w2, const float* __restrict__ w3,
    f16* __restrict__ o0, f16* __restrict__ o1,
    f16* __restrict__ o2, f16* __restrict__ o3)
{
    const float* src; f16* dst;
    switch (blockIdx.z) {
        case 0:  src = w0; dst = o0; break;
        case 1:  src = w1; dst = o1; break;
        case 2:  src = w2; dst = o2; break;
        default: src = w3; dst = o3; break;
    }
    const int idx = (blockIdx.x * 256 + threadIdx.x) * 4;
    const float4 v = *(const float4*)(src + idx);
    half4 h; h[0] = (f16)v.x; h[1] = (f16)v.y; h[2] = (f16)v.z; h[3] = (f16)v.w;
    *(half4*)(dst + idx) = h;
}

// ---------------------------------------------------------------------------
// x [B][C][T] fp32 -> xt [B][T][C] fp16 (32x32 LDS tile transpose)
// ---------------------------------------------------------------------------
__global__ __launch_bounds__(256) void transpose_x_kernel(
    const float* __restrict__ x, f16* __restrict__ xt)
{
    __shared__ float xs[32][33];
    const int b  = blockIdx.z;
    const int t0 = blockIdx.x * 32, c0 = blockIdx.y * 32;
    const float* xb = x + (size_t)b * C_DIM * T_DIM;
    const int r = threadIdx.x >> 3, q = threadIdx.x & 7;

    const float4 v = *(const float4*)(xb + (size_t)(c0 + r) * T_DIM + t0 + q * 4);
    xs[r][q * 4 + 0] = v.x; xs[r][q * 4 + 1] = v.y;
    xs[r][q * 4 + 2] = v.z; xs[r][q * 4 + 3] = v.w;
    __syncthreads();

    f16* xtb = xt + (size_t)b * C_DIM * T_DIM;
    half4 h;
    h[0] = (f16)xs[q * 4 + 0][r]; h[1] = (f16)xs[q * 4 + 1][r];
    h[2] = (f16)xs[q * 4 + 2][r]; h[3] = (f16)xs[q * 4 + 3][r];
    *(half4*)(xtb + (size_t)(t0 + r) * C_DIM + c0 + q * 4) = h;
}

// ---------------------------------------------------------------------------
// Generic TN MFMA GEMM: C[i][j] = sum_k A[i][k] * B[j][k]  (both K-contiguous)
// 128x128 block tile, BK=32, 4 waves each computing a 64x64 sub-tile via
// 4x4 grid of 16x16x32 f16 MFMAs. MODE: 0 = f16 plain store;
// 1 = f16 relu(+bias[col]); 2 = f16 relu(+bias[row]);
// 3 = fp32 relu(+bias[row]) + resid.
// ---------------------------------------------------------------------------
template<int MODE>
__global__ __launch_bounds__(256) void gemm_tn(
    const f16* __restrict__ A, size_t sA, int lda,
    const f16* __restrict__ B, size_t sB, int ldb,
    void* __restrict__ Cp, size_t sC, int ldc,
    const float* __restrict__ bias,
    const float* __restrict__ resid, size_t sR,
    int K)
{
    __shared__ __align__(16) f16 As[128 * LDSK];
    __shared__ __align__(16) f16 Bs[128 * LDSK];

    const int bz = blockIdx.z;
    const int i0 = blockIdx.y * 128, j0 = blockIdx.x * 128;
    A += (size_t)bz * sA;
    B += (size_t)bz * sB;

    const int tid  = threadIdx.x;
    const int lane = tid & 63;
    const int wave = tid >> 6;
    const int wy = wave >> 1, wx = wave & 1;
    const int quad = lane >> 4, l16 = lane & 15;

    // staging: 512 16B-chunks per tile (128 rows x 4 chunks); 2 chunks/thread
    const int c1 = tid, c2 = tid + 256;
    const int row1 = c1 >> 2, ch1 = c1 & 3;
    const int row2 = c2 >> 2, ch2 = c2 & 3;

    floatx4 acc[4][4] = {};

    for (int k0 = 0; k0 < K; k0 += 32) {
        const float4 a1 = *(const float4*)(A + (size_t)(i0 + row1) * lda + k0 + ch1 * 8);
        const float4 a2 = *(const float4*)(A + (size_t)(i0 + row2) * lda + k0 + ch2 * 8);
        const float4 b1 = *(const float4*)(B + (size_t)(j0 + row1) * ldb + k0 + ch1 * 8);
        const float4 b2 = *(const float4*)(B + (size_t)(j0 + row2) * ldb + k0 + ch2 * 8);
        __syncthreads();   // previous iteration's frag reads must finish
        *(float4*)&As[row1 * LDSK + ch1 * 8] = a1;
        *(float4*)&As[row2 * LDSK + ch2 * 8] = a2;
        *(float4*)&Bs[row1 * LDSK + ch1 * 8] = b1;
        *(float4*)&Bs[row2 * LDSK + ch2 * 8] = b2;
        __syncthreads();

        half8 af[4], bf[4];
        #pragma unroll
        for (int mi = 0; mi < 4; ++mi)
            af[mi] = *(const half8*)&As[(wy * 64 + mi * 16 + l16) * LDSK + quad * 8];
        #pragma unroll
        for (int ni = 0; ni < 4; ++ni)
            bf[ni] = *(const half8*)&Bs[(wx * 64 + ni * 16 + l16) * LDSK + quad * 8];
        #pragma unroll
        for (int mi = 0; mi < 4; ++mi)
            #pragma unroll
            for (int ni = 0; ni < 4; ++ni)
                acc[mi][ni] = __builtin_amdgcn_mfma_f32_16x16x32_f16(
                    af[mi], bf[ni], acc[mi][ni], 0, 0, 0);
    }

    // epilogue: C/D layout col = lane&15, row = quad*4 + reg (m89-verified)
    #pragma unroll
    for (int mi = 0; mi < 4; ++mi) {
        #pragma unroll
        for (int ni = 0; ni < 4; ++ni) {
            const int col = j0 + wx * 64 + ni * 16 + l16;
            #pragma unroll
            for (int r = 0; r < 4; ++r) {
                const int row = i0 + wy * 64 + mi * 16 + quad * 4 + r;
                float v = acc[mi][ni][r];
                if (MODE == 1) { v += bias[col]; v = v > 0.f ? v : 0.f; }
                if (MODE == 2) { v += bias[row]; v = v > 0.f ? v : 0.f; }
                if (MODE == 3) {
                    v += bias[row];
                    v = v > 0.f ? v : 0.f;
                    v += resid[(size_t)bz * sR + (size_t)row * ldc + col];
                    ((float*)Cp)[(size_t)bz * sC + (size_t)row * ldc + col] = v;
                } else {
                    ((f16*)Cp)[(size_t)bz * sC + (size_t)row * ldc + col] = (f16)v;
                }
            }
        }
    }
}

// ---------------------------------------------------------------------------
// in-place fp16 softmax over rows of 2048 (fp32 math)
// ---------------------------------------------------------------------------
__global__ __launch_bounds__(256) void softmax_f16_kernel(f16* __restrict__ S)
{
    f16* p = S + (size_t)blockIdx.x * T_DIM;
    const int tid = threadIdx.x;

    half8 hv = *((const half8*)p + tid);
    float v[8];
    float lmax = -1e30f;
    #pragma unroll
    for (int c = 0; c < 8; ++c) { v[c] = (float)hv[c]; lmax = fmaxf(lmax, v[c]); }
    #pragma unroll
    for (int off = 32; off; off >>= 1)
        lmax = fmaxf(lmax, __shfl_down(lmax, off));
    __shared__ float redm[4];
    if ((tid & 63) == 0) redm[tid >> 6] = lmax;
    __syncthreads();
    const float m = fmaxf(fmaxf(redm[0], redm[1]), fmaxf(redm[2], redm[3]));

    float lsum = 0.f;
    #pragma unroll
    for (int c = 0; c < 8; ++c) { v[c] = __expf(v[c] - m); lsum += v[c]; }
    #pragma unroll
    for (int off = 32; off; off >>= 1)
        lsum += __shfl_down(lsum, off);
    __shared__ float reds[4];
    if ((tid & 63) == 0) reds[tid >> 6] = lsum;
    __syncthreads();
    const float inv = 1.f / (reds[0] + reds[1] + reds[2] + reds[3]);

    #pragma unroll
    for (int c = 0; c < 8; ++c) hv[c] = (f16)(v[c] * inv);
    *((half8*)p + tid) = hv;
}

// ---------------------------------------------------------------------------
extern "C" void kernel_launch(void* const* d_in, const int* in_sizes, int n_in,
                              void* d_out, int out_size, void* d_ws, size_t ws_size,
                              hipStream_t stream)
{
    const float* x       = (const float*)d_in[0];
    const float* w_theta = (const float*)d_in[1];
    const float* b_theta = (const float*)d_in[2];
    const float* w_phi   = (const float*)d_in[3];
    const float* b_phi   = (const float*)d_in[4];
    const float* w_g     = (const float*)d_in[5];
    const float* b_g     = (const float*)d_in[6];
    const float* w_w     = (const float*)d_in[7];
    const float* b_w     = (const float*)d_in[8];
    float* out = (float*)d_out;

    const size_t FE = (size_t)B_DIM * C_DIM * T_DIM;   // 8.4M
    const size_t TC = (size_t)T_DIM * C_DIM;           // per-batch feat elems
    const size_t TT = (size_t)T_DIM * T_DIM;

    f16* xt      = (f16*)d_ws;
    f16* wt      = xt + FE;
    f16* wtheta_h = wt;
    f16* wphi_h   = wt + 262144;
    f16* wg_h     = wt + 524288;
    f16* ww_h     = wt + 786432;
    f16* theta   = wt + 1048576;
    f16* phi     = theta + FE;
    f16* g       = phi + FE;
    f16* scores  = g + FE;          // B*T*T fp16 = 67 MB
    f16* feature = theta;           // theta dead after scores

    const dim3 blk(256);

    convert_w_kernel<<<dim3(256, 1, 4), blk, 0, stream>>>(
        w_theta, w_phi, w_g, w_w, wtheta_h, wphi_h, wg_h, ww_h);
    transpose_x_kernel<<<dim3(T_DIM / 32, C_DIM / 32, B_DIM), blk, 0, stream>>>(x, xt);

    // theta_t[i][c] = relu(xt . w_theta + b[c])   M=T, N=C
    gemm_tn<1><<<dim3(C_DIM / 128, T_DIM / 128, B_DIM), blk, 0, stream>>>(
        xt, TC, C_DIM, wtheta_h, 0, C_DIM, theta, TC, C_DIM, b_theta, nullptr, 0, C_DIM);
    // phi_t
    gemm_tn<1><<<dim3(C_DIM / 128, T_DIM / 128, B_DIM), blk, 0, stream>>>(
        xt, TC, C_DIM, wphi_h, 0, C_DIM, phi, TC, C_DIM, b_phi, nullptr, 0, C_DIM);
    // g[c][t] = relu(w_g . xt + b[c])   M=C, N=T
    gemm_tn<2><<<dim3(T_DIM / 128, C_DIM / 128, B_DIM), blk, 0, stream>>>(
        wg_h, 0, C_DIM, xt, TC, C_DIM, g, TC, T_DIM, b_g, nullptr, 0, C_DIM);
    // scores[i][j] = theta_t . phi_t   M=T, N=T
    gemm_tn<0><<<dim3(T_DIM / 128, T_DIM / 128, B_DIM), blk, 0, stream>>>(
        theta, TC, C_DIM, phi, TC, C_DIM, scores, TT, T_DIM, nullptr, nullptr, 0, C_DIM);
    // softmax rows, in place
    softmax_f16_kernel<<<dim3(B_DIM * T_DIM), blk, 0, stream>>>(scores);
    // feature_t[i][c] = attn . g   M=T, N=C, K=T
    gemm_tn<0><<<dim3(C_DIM / 128, T_DIM / 128, B_DIM), blk, 0, stream>>>(
        scores, TT, T_DIM, g, TC, T_DIM, feature, TC, C_DIM, nullptr, nullptr, 0, T_DIM);
    // out[c][t] = relu(w_w . feature_t + b[c]) + x   M=C, N=T
    gemm_tn<3><<<dim3(T_DIM / 128, C_DIM / 128, B_DIM), blk, 0, stream>>>(
        ww_h, 0, C_DIM, feature, TC, C_DIM, out, TC, T_DIM, b_w, x, TC, C_DIM);
}

// Round 3
// 312.365 us; speedup vs baseline: 4.5286x; 1.0216x over previous
//
#include <hip/hip_runtime.h>
#include <math.h>

#define C_DIM 512
#define T_DIM 2048
#define B_DIM 8

typedef _Float16 f16;
typedef __attribute__((ext_vector_type(8))) _Float16 half8;
typedef __attribute__((ext_vector_type(4))) _Float16 half4;
typedef __attribute__((ext_vector_type(4))) float floatx4;

typedef __attribute__((address_space(1))) void gvoid;
typedef __attribute__((address_space(3))) void lvoid;

__device__ __forceinline__ void gl_lds16(const f16* g, f16* l) {
    // async global->LDS DMA, 16 B/lane; LDS dest = wave-uniform base + lane*16
    __builtin_amdgcn_global_load_lds((gvoid*)g, (lvoid*)l, 16, 0, 0);
}

// ---------------------------------------------------------------------------
// fp32 [512][512] weights -> fp16
// ---------------------------------------------------------------------------
__global__ __launch_bounds__(256) void convert_w_kernel(
    const float* __restrict__ w0, const float* __restrict__ w1,
    const float* __restrict__ w2, const float* __restrict__ w3,
    f16* __restrict__ o0, f16* __restrict__ o1,
    f16* __restrict__ o2, f16* __restrict__ o3)
{
    const float* src; f16* dst;
    switch (blockIdx.z) {
        case 0:  src = w0; dst = o0; break;
        case 1:  src = w1; dst = o1; break;
        case 2:  src = w2; dst = o2; break;
        default: src = w3; dst = o3; break;
    }
    const int idx = (blockIdx.x * 256 + threadIdx.x) * 4;
    const float4 v = *(const float4*)(src + idx);
    half4 h; h[0] = (f16)v.x; h[1] = (f16)v.y; h[2] = (f16)v.z; h[3] = (f16)v.w;
    *(half4*)(dst + idx) = h;
}

// ---------------------------------------------------------------------------
// x [B][C][T] fp32 -> xt [B][T][C] fp16 (32x32 LDS tile transpose)
// ---------------------------------------------------------------------------
__global__ __launch_bounds__(256) void transpose_x_kernel(
    const float* __restrict__ x, f16* __restrict__ xt)
{
    __shared__ float xs[32][33];
    const int b  = blockIdx.z;
    const int t0 = blockIdx.x * 32, c0 = blockIdx.y * 32;
    const float* xb = x + (size_t)b * C_DIM * T_DIM;
    const int r = threadIdx.x >> 3, q = threadIdx.x & 7;

    const float4 v = *(const float4*)(xb + (size_t)(c0 + r) * T_DIM + t0 + q * 4);
    xs[r][q * 4 + 0] = v.x; xs[r][q * 4 + 1] = v.y;
    xs[r][q * 4 + 2] = v.z; xs[r][q * 4 + 3] = v.w;
    __syncthreads();

    f16* xtb = xt + (size_t)b * C_DIM * T_DIM;
    half4 h;
    h[0] = (f16)xs[q * 4 + 0][r]; h[1] = (f16)xs[q * 4 + 1][r];
    h[2] = (f16)xs[q * 4 + 2][r]; h[3] = (f16)xs[q * 4 + 3][r];
    *(half4*)(xtb + (size_t)(t0 + r) * C_DIM + c0 + q * 4) = h;
}

// ---------------------------------------------------------------------------
// TN MFMA GEMM: C[i][j] = sum_k A[i][k] * B[j][k]
// 128x128 tile, BK=32, global_load_lds dwordx4 staging (m97 structure),
// XOR chunk swizzle (cc = q ^ (row&3)) cuts frag-read conflicts 8-way->4-way.
// MODE: 0 = f16 store; 1 = f16 relu(+bias[col]); 2 = f16 relu(+bias[row]);
// 3 = fp32 relu(+bias[row]) + resid.
// ---------------------------------------------------------------------------
template<int MODE>
__global__ __launch_bounds__(256) void gemm_tn(
    const f16* __restrict__ A, size_t sA, int lda,
    const f16* __restrict__ B, size_t sB, int ldb,
    void* __restrict__ Cp, size_t sC, int ldc,
    const float* __restrict__ bias,
    const float* __restrict__ resid, size_t sR,
    int K)
{
    __shared__ __align__(16) f16 As[128 * 32];   // 8 KB, unpadded (DMA layout)
    __shared__ __align__(16) f16 Bs[128 * 32];

    // 4x4-supertile block swizzle: 16 consecutive blocks share 4 A + 4 B tiles
    const int gx = gridDim.x;                 // multiple of 4 for all our shapes
    const int flat = blockIdx.y * gx + blockIdx.x;
    const int jsc = gx >> 2;                  // supertiles per row (1 or 4)
    const int sh = (jsc == 1) ? 0 : ((jsc == 4) ? 2 : (31 - __builtin_clz(jsc)));
    const int s = flat >> 4, rem = flat & 15;
    const int i0 = ((s >> sh) * 4 + (rem >> 2)) * 128;
    const int j0 = ((s & (jsc - 1)) * 4 + (rem & 3)) * 128;

    const int bz = blockIdx.z;
    A += (size_t)bz * sA;
    B += (size_t)bz * sB;

    const int tid  = threadIdx.x;
    const int lane = tid & 63;
    const int wave = tid >> 6;
    const int wy = wave >> 1, wx = wave & 1;
    const int quad = lane >> 4, l16 = lane & 15;

    // DMA chunk plan: tile = 512 x 16B chunks; wave w instr q covers chunks
    // w*128 + q*64 + lane. Physical chunk c -> row c>>2, logical k-chunk
    // (c&3) ^ (row&3)  (XOR swizzle).
    const int cb0 = wave * 128,      cb1 = wave * 128 + 64;
    const int r0  = (cb0 + lane) >> 2, r1 = (cb1 + lane) >> 2;
    const int q0  = ((cb0 + lane) & 3) ^ (r0 & 3);
    const int q1  = ((cb1 + lane) & 3) ^ (r1 & 3);

    const f16* gA0 = A + (size_t)(i0 + r0) * lda + q0 * 8;
    const f16* gA1 = A + (size_t)(i0 + r1) * lda + q1 * 8;
    const f16* gB0 = B + (size_t)(j0 + r0) * ldb + q0 * 8;
    const f16* gB1 = B + (size_t)(j0 + r1) * ldb + q1 * 8;
    f16* lA0 = As + cb0 * 8;   // wave-uniform LDS bases (halves)
    f16* lA1 = As + cb1 * 8;
    f16* lB0 = Bs + cb0 * 8;
    f16* lB1 = Bs + cb1 * 8;

    // frag-read chunk slot: cc = quad ^ (row&3); row&3 == l16&3 here
    const int xa = (quad ^ (l16 & 3)) << 3;   // halves offset within row

    floatx4 acc[4][4] = {};

    for (int k0 = 0; k0 < K; k0 += 32) {
        __syncthreads();                       // prev tile's frag reads done
        gl_lds16(gA0 + k0, lA0);
        gl_lds16(gA1 + k0, lA1);
        gl_lds16(gB0 + k0, lB0);
        gl_lds16(gB1 + k0, lB1);
        __syncthreads();                       // vmcnt(0) drained at barrier

        half8 af[4], bf[4];
        #pragma unroll
        for (int mi = 0; mi < 4; ++mi)
            af[mi] = *(const half8*)&As[(wy * 64 + mi * 16 + l16) * 32 + xa];
        #pragma unroll
        for (int ni = 0; ni < 4; ++ni)
            bf[ni] = *(const half8*)&Bs[(wx * 64 + ni * 16 + l16) * 32 + xa];
        #pragma unroll
        for (int mi = 0; mi < 4; ++mi)
            #pragma unroll
            for (int ni = 0; ni < 4; ++ni)
                acc[mi][ni] = __builtin_amdgcn_mfma_f32_16x16x32_f16(
                    af[mi], bf[ni], acc[mi][ni], 0, 0, 0);
    }

    // epilogue: C/D layout col = lane&15, row = quad*4 + reg (m89-verified)
    #pragma unroll
    for (int mi = 0; mi < 4; ++mi) {
        #pragma unroll
        for (int ni = 0; ni < 4; ++ni) {
            const int col = j0 + wx * 64 + ni * 16 + l16;
            #pragma unroll
            for (int r = 0; r < 4; ++r) {
                const int row = i0 + wy * 64 + mi * 16 + quad * 4 + r;
                float v = acc[mi][ni][r];
                if (MODE == 1) { v += bias[col]; v = v > 0.f ? v : 0.f; }
                if (MODE == 2) { v += bias[row]; v = v > 0.f ? v : 0.f; }
                if (MODE == 3) {
                    v += bias[row];
                    v = v > 0.f ? v : 0.f;
                    v += resid[(size_t)bz * sR + (size_t)row * ldc + col];
                    ((float*)Cp)[(size_t)bz * sC + (size_t)row * ldc + col] = v;
                } else {
                    ((f16*)Cp)[(size_t)bz * sC + (size_t)row * ldc + col] = (f16)v;
                }
            }
        }
    }
}

// ---------------------------------------------------------------------------
// in-place fp16 softmax over rows of 2048 (fp32 math)
// ---------------------------------------------------------------------------
__global__ __launch_bounds__(256) void softmax_f16_kernel(f16* __restrict__ S)
{
    f16* p = S + (size_t)blockIdx.x * T_DIM;
    const int tid = threadIdx.x;

    half8 hv = *((const half8*)p + tid);
    float v[8];
    float lmax = -1e30f;
    #pragma unroll
    for (int c = 0; c < 8; ++c) { v[c] = (float)hv[c]; lmax = fmaxf(lmax, v[c]); }
    #pragma unroll
    for (int off = 32; off; off >>= 1)
        lmax = fmaxf(lmax, __shfl_down(lmax, off));
    __shared__ float redm[4];
    if ((tid & 63) == 0) redm[tid >> 6] = lmax;
    __syncthreads();
    const float m = fmaxf(fmaxf(redm[0], redm[1]), fmaxf(redm[2], redm[3]));

    float lsum = 0.f;
    #pragma unroll
    for (int c = 0; c < 8; ++c) { v[c] = __expf(v[c] - m); lsum += v[c]; }
    #pragma unroll
    for (int off = 32; off; off >>= 1)
        lsum += __shfl_down(lsum, off);
    __shared__ float reds[4];
    if ((tid & 63) == 0) reds[tid >> 6] = lsum;
    __syncthreads();
    const float inv = 1.f / (reds[0] + reds[1] + reds[2] + reds[3]);

    #pragma unroll
    for (int c = 0; c < 8; ++c) hv[c] = (f16)(v[c] * inv);
    *((half8*)p + tid) = hv;
}

// ---------------------------------------------------------------------------
extern "C" void kernel_launch(void* const* d_in, const int* in_sizes, int n_in,
                              void* d_out, int out_size, void* d_ws, size_t ws_size,
                              hipStream_t stream)
{
    const float* x       = (const float*)d_in[0];
    const float* w_theta = (const float*)d_in[1];
    const float* b_theta = (const float*)d_in[2];
    const float* w_phi   = (const float*)d_in[3];
    const float* b_phi   = (const float*)d_in[4];
    const float* w_g     = (const float*)d_in[5];
    const float* b_g     = (const float*)d_in[6];
    const float* w_w     = (const float*)d_in[7];
    const float* b_w     = (const float*)d_in[8];
    float* out = (float*)d_out;

    const size_t FE = (size_t)B_DIM * C_DIM * T_DIM;   // 8.4M
    const size_t TC = (size_t)T_DIM * C_DIM;
    const size_t TT = (size_t)T_DIM * T_DIM;

    f16* xt       = (f16*)d_ws;
    f16* wt       = xt + FE;
    f16* wtheta_h = wt;
    f16* wphi_h   = wt + 262144;
    f16* wg_h     = wt + 524288;
    f16* ww_h     = wt + 786432;
    f16* theta    = wt + 1048576;
    f16* phi      = theta + FE;
    f16* g        = phi + FE;
    f16* scores   = g + FE;          // B*T*T fp16 = 67 MB
    f16* feature  = theta;           // theta dead after scores

    const dim3 blk(256);

    convert_w_kernel<<<dim3(256, 1, 4), blk, 0, stream>>>(
        w_theta, w_phi, w_g, w_w, wtheta_h, wphi_h, wg_h, ww_h);
    transpose_x_kernel<<<dim3(T_DIM / 32, C_DIM / 32, B_DIM), blk, 0, stream>>>(x, xt);

    gemm_tn<1><<<dim3(C_DIM / 128, T_DIM / 128, B_DIM), blk, 0, stream>>>(
        xt, TC, C_DIM, wtheta_h, 0, C_DIM, theta, TC, C_DIM, b_theta, nullptr, 0, C_DIM);
    gemm_tn<1><<<dim3(C_DIM / 128, T_DIM / 128, B_DIM), blk, 0, stream>>>(
        xt, TC, C_DIM, wphi_h, 0, C_DIM, phi, TC, C_DIM, b_phi, nullptr, 0, C_DIM);
    gemm_tn<2><<<dim3(T_DIM / 128, C_DIM / 128, B_DIM), blk, 0, stream>>>(
        wg_h, 0, C_DIM, xt, TC, C_DIM, g, TC, T_DIM, b_g, nullptr, 0, C_DIM);
    gemm_tn<0><<<dim3(T_DIM / 128, T_DIM / 128, B_DIM), blk, 0, stream>>>(
        theta, TC, C_DIM, phi, TC, C_DIM, scores, TT, T_DIM, nullptr, nullptr, 0, C_DIM);
    softmax_f16_kernel<<<dim3(B_DIM * T_DIM), blk, 0, stream>>>(scores);
    gemm_tn<0><<<dim3(C_DIM / 128, T_DIM / 128, B_DIM), blk, 0, stream>>>(
        scores, TT, T_DIM, g, TC, T_DIM, feature, TC, C_DIM, nullptr, nullptr, 0, T_DIM);
    gemm_tn<3><<<dim3(T_DIM / 128, C_DIM / 128, B_DIM), blk, 0, stream>>>(
        ww_h, 0, C_DIM, feature, TC, C_DIM, out, TC, T_DIM, b_w, x, TC, C_DIM);
}

// Round 4
// 298.111 us; speedup vs baseline: 4.7451x; 1.0478x over previous
//
#include <hip/hip_runtime.h>
#include <math.h>

#define C_DIM 512
#define T_DIM 2048
#define B_DIM 8

typedef _Float16 f16;
typedef __attribute__((ext_vector_type(8))) _Float16 half8;
typedef __attribute__((ext_vector_type(4))) _Float16 half4;
typedef __attribute__((ext_vector_type(4))) float floatx4;

typedef __attribute__((address_space(1))) void gvoid;
typedef __attribute__((address_space(3))) void lvoid;

__device__ __forceinline__ void gl_lds16(const f16* g, f16* l) {
    // async global->LDS DMA, 16 B/lane; LDS dest = wave-uniform base + lane*16
    __builtin_amdgcn_global_load_lds((gvoid*)g, (lvoid*)l, 16, 0, 0);
}

// ---------------------------------------------------------------------------
// fp32 [512][512] weights -> fp16. z=0/1 write into the merged [1024][512]
// theta|phi buffer; z=2/3 -> wg, ww.
// ---------------------------------------------------------------------------
__global__ __launch_bounds__(256) void convert_w_kernel(
    const float* __restrict__ w0, const float* __restrict__ w1,
    const float* __restrict__ w2, const float* __restrict__ w3,
    f16* __restrict__ o0, f16* __restrict__ o1,
    f16* __restrict__ o2, f16* __restrict__ o3)
{
    const float* src; f16* dst;
    switch (blockIdx.z) {
        case 0:  src = w0; dst = o0; break;
        case 1:  src = w1; dst = o1; break;
        case 2:  src = w2; dst = o2; break;
        default: src = w3; dst = o3; break;
    }
    const int idx = (blockIdx.x * 256 + threadIdx.x) * 4;
    const float4 v = *(const float4*)(src + idx);
    half4 h; h[0] = (f16)v.x; h[1] = (f16)v.y; h[2] = (f16)v.z; h[3] = (f16)v.w;
    *(half4*)(dst + idx) = h;
}

__global__ __launch_bounds__(256) void concat_bias_kernel(
    const float* __restrict__ b0, const float* __restrict__ b1,
    float* __restrict__ o)
{
    const int i = blockIdx.x * 256 + threadIdx.x;   // 1024 threads
    o[i] = (i < 512) ? b0[i] : b1[i - 512];
}

// ---------------------------------------------------------------------------
// x [B][C][T] fp32 -> xt [B][T][C] fp16 (32x32 LDS tile transpose)
// ---------------------------------------------------------------------------
__global__ __launch_bounds__(256) void transpose_x_kernel(
    const float* __restrict__ x, f16* __restrict__ xt)
{
    __shared__ float xs[32][33];
    const int b  = blockIdx.z;
    const int t0 = blockIdx.x * 32, c0 = blockIdx.y * 32;
    const float* xb = x + (size_t)b * C_DIM * T_DIM;
    const int r = threadIdx.x >> 3, q = threadIdx.x & 7;

    const float4 v = *(const float4*)(xb + (size_t)(c0 + r) * T_DIM + t0 + q * 4);
    xs[r][q * 4 + 0] = v.x; xs[r][q * 4 + 1] = v.y;
    xs[r][q * 4 + 2] = v.z; xs[r][q * 4 + 3] = v.w;
    __syncthreads();

    f16* xtb = xt + (size_t)b * C_DIM * T_DIM;
    half4 h;
    h[0] = (f16)xs[q * 4 + 0][r]; h[1] = (f16)xs[q * 4 + 1][r];
    h[2] = (f16)xs[q * 4 + 2][r]; h[3] = (f16)xs[q * 4 + 3][r];
    *(half4*)(xtb + (size_t)(t0 + r) * C_DIM + c0 + q * 4) = h;
}

// ---------------------------------------------------------------------------
// TN MFMA GEMM: C[i][j] = sum_k A[i][k] * B[j][k]
// 128x128 tile, BK=32, global_load_lds staging, EXPLICIT LDS DOUBLE BUFFER:
// DMA for tile k+1 issued right after the barrier, before computing tile k,
// so next barrier's vmcnt(0) drain waits on an already-landed DMA.
// XOR chunk swizzle (slot = q ^ (row&3)) keeps frag reads at 4-way.
// MODE: 0 = f16 store; 1 = f16 relu(+bias[col]); 2 = f16 relu(+bias[row]);
// 3 = fp32 relu(+bias[row]) + resid.
// ---------------------------------------------------------------------------
template<int MODE>
__global__ __launch_bounds__(256) void gemm_tn(
    const f16* __restrict__ A, size_t sA, int lda,
    const f16* __restrict__ B, size_t sB, int ldb,
    void* __restrict__ Cp, size_t sC, int ldc,
    const float* __restrict__ bias,
    const float* __restrict__ resid, size_t sR,
    int K)
{
    __shared__ __align__(16) f16 As[2][128 * 32];   // 2 x 8 KB
    __shared__ __align__(16) f16 Bs[2][128 * 32];

    // 4x4-supertile block swizzle: 16 consecutive blocks share 4 A + 4 B tiles
    const int gx = gridDim.x;
    const int flat = blockIdx.y * gx + blockIdx.x;
    const int jsc = gx >> 2;                  // j-supertiles per row
    const int sh = (jsc <= 1) ? 0 : (31 - __builtin_clz(jsc));
    const int s = flat >> 4, rem = flat & 15;
    const int i0 = ((s >> sh) * 4 + (rem >> 2)) * 128;
    const int j0 = (((jsc <= 1) ? 0 : (s & (jsc - 1))) * 4 + (rem & 3)) * 128;

    const int bz = blockIdx.z;
    A += (size_t)bz * sA;
    B += (size_t)bz * sB;

    const int tid  = threadIdx.x;
    const int lane = tid & 63;
    const int wave = tid >> 6;
    const int wy = wave >> 1, wx = wave & 1;
    const int quad = lane >> 4, l16 = lane & 15;

    // DMA chunk plan: 512 x 16B chunks/tile; wave w covers chunks w*128..+127
    // physical chunk c -> row c>>2, k-chunk slot (c&3), holding logical
    // k-chunk (c&3)^(row&3) (XOR swizzle applied on the SOURCE address).
    const int cb0 = wave * 128,      cb1 = wave * 128 + 64;
    const int r0  = (cb0 + lane) >> 2, r1 = (cb1 + lane) >> 2;
    const int q0  = ((cb0 + lane) & 3) ^ (r0 & 3);
    const int q1  = ((cb1 + lane) & 3) ^ (r1 & 3);

    const f16* gA0 = A + (size_t)(i0 + r0) * lda + q0 * 8;
    const f16* gA1 = A + (size_t)(i0 + r1) * lda + q1 * 8;
    const f16* gB0 = B + (size_t)(j0 + r0) * ldb + q0 * 8;
    const f16* gB1 = B + (size_t)(j0 + r1) * ldb + q1 * 8;

    // frag-read slot: quad ^ (row&3); row&3 == l16&3 for all frag rows
    const int xa = (quad ^ (l16 & 3)) << 3;   // halves offset within row

    floatx4 acc[4][4] = {};

    // prologue: DMA tile 0 into buffer 0
    gl_lds16(gA0, &As[0][cb0 * 8]);
    gl_lds16(gA1, &As[0][cb1 * 8]);
    gl_lds16(gB0, &Bs[0][cb0 * 8]);
    gl_lds16(gB1, &Bs[0][cb1 * 8]);

    for (int k0 = 0; k0 < K; k0 += 32) {
        const int p = (k0 >> 5) & 1;
        __syncthreads();                 // drains DMA issued one iter ago
        if (k0 + 32 < K) {               // prefetch next tile into other buf
            const int pn = p ^ 1;
            gl_lds16(gA0 + k0 + 32, &As[pn][cb0 * 8]);
            gl_lds16(gA1 + k0 + 32, &As[pn][cb1 * 8]);
            gl_lds16(gB0 + k0 + 32, &Bs[pn][cb0 * 8]);
            gl_lds16(gB1 + k0 + 32, &Bs[pn][cb1 * 8]);
        }

        half8 af[4], bf[4];
        #pragma unroll
        for (int mi = 0; mi < 4; ++mi)
            af[mi] = *(const half8*)&As[p][(wy * 64 + mi * 16 + l16) * 32 + xa];
        #pragma unroll
        for (int ni = 0; ni < 4; ++ni)
            bf[ni] = *(const half8*)&Bs[p][(wx * 64 + ni * 16 + l16) * 32 + xa];
        #pragma unroll
        for (int mi = 0; mi < 4; ++mi)
            #pragma unroll
            for (int ni = 0; ni < 4; ++ni)
                acc[mi][ni] = __builtin_amdgcn_mfma_f32_16x16x32_f16(
                    af[mi], bf[ni], acc[mi][ni], 0, 0, 0);
    }

    // epilogue: C/D layout col = lane&15, row = quad*4 + reg (m89-verified)
    #pragma unroll
    for (int mi = 0; mi < 4; ++mi) {
        #pragma unroll
        for (int ni = 0; ni < 4; ++ni) {
            const int col = j0 + wx * 64 + ni * 16 + l16;
            #pragma unroll
            for (int r = 0; r < 4; ++r) {
                const int row = i0 + wy * 64 + mi * 16 + quad * 4 + r;
                float v = acc[mi][ni][r];
                if (MODE == 1) { v += bias[col]; v = v > 0.f ? v : 0.f; }
                if (MODE == 2) { v += bias[row]; v = v > 0.f ? v : 0.f; }
                if (MODE == 3) {
                    v += bias[row];
                    v = v > 0.f ? v : 0.f;
                    v += resid[(size_t)bz * sR + (size_t)row * ldc + col];
                    ((float*)Cp)[(size_t)bz * sC + (size_t)row * ldc + col] = v;
                } else {
                    ((f16*)Cp)[(size_t)bz * sC + (size_t)row * ldc + col] = (f16)v;
                }
            }
        }
    }
}

// ---------------------------------------------------------------------------
// in-place fp16 softmax over rows of 2048 (fp32 math)
// ---------------------------------------------------------------------------
__global__ __launch_bounds__(256) void softmax_f16_kernel(f16* __restrict__ S)
{
    f16* p = S + (size_t)blockIdx.x * T_DIM;
    const int tid = threadIdx.x;

    half8 hv = *((const half8*)p + tid);
    float v[8];
    float lmax = -1e30f;
    #pragma unroll
    for (int c = 0; c < 8; ++c) { v[c] = (float)hv[c]; lmax = fmaxf(lmax, v[c]); }
    #pragma unroll
    for (int off = 32; off; off >>= 1)
        lmax = fmaxf(lmax, __shfl_down(lmax, off));
    __shared__ float redm[4];
    if ((tid & 63) == 0) redm[tid >> 6] = lmax;
    __syncthreads();
    const float m = fmaxf(fmaxf(redm[0], redm[1]), fmaxf(redm[2], redm[3]));

    float lsum = 0.f;
    #pragma unroll
    for (int c = 0; c < 8; ++c) { v[c] = __expf(v[c] - m); lsum += v[c]; }
    #pragma unroll
    for (int off = 32; off; off >>= 1)
        lsum += __shfl_down(lsum, off);
    __shared__ float reds[4];
    if ((tid & 63) == 0) reds[tid >> 6] = lsum;
    __syncthreads();
    const float inv = 1.f / (reds[0] + reds[1] + reds[2] + reds[3]);

    #pragma unroll
    for (int c = 0; c < 8; ++c) hv[c] = (f16)(v[c] * inv);
    *((half8*)p + tid) = hv;
}

// ---------------------------------------------------------------------------
extern "C" void kernel_launch(void* const* d_in, const int* in_sizes, int n_in,
                              void* d_out, int out_size, void* d_ws, size_t ws_size,
                              hipStream_t stream)
{
    const float* x       = (const float*)d_in[0];
    const float* w_theta = (const float*)d_in[1];
    const float* b_theta = (const float*)d_in[2];
    const float* w_phi   = (const float*)d_in[3];
    const float* b_phi   = (const float*)d_in[4];
    const float* w_g     = (const float*)d_in[5];
    const float* b_g     = (const float*)d_in[6];
    const float* w_w     = (const float*)d_in[7];
    const float* b_w     = (const float*)d_in[8];
    float* out = (float*)d_out;

    const size_t FE = (size_t)B_DIM * C_DIM * T_DIM;   // 8.4M
    const size_t TC = (size_t)T_DIM * C_DIM;
    const size_t TT = (size_t)T_DIM * T_DIM;

    f16* xt      = (f16*)d_ws;
    f16* wtp     = xt + FE;              // merged theta|phi weights [1024][512]
    f16* wg_h    = wtp + 524288;
    f16* ww_h    = wg_h + 262144;
    float* btp   = (float*)(ww_h + 262144);   // merged bias [1024] fp32
    f16* tp      = (f16*)(btp + 1024);   // theta|phi acts [B][T][1024]
    f16* g       = tp + (size_t)B_DIM * T_DIM * 1024;
    f16* scores  = g + FE;               // B*T*T fp16 = 67 MB
    f16* feature = tp;                   // tp dead after scores GEMM

    const dim3 blk(256);

    convert_w_kernel<<<dim3(256, 1, 4), blk, 0, stream>>>(
        w_theta, w_phi, w_g, w_w, wtp, wtp + 262144, wg_h, ww_h);
    concat_bias_kernel<<<dim3(4), blk, 0, stream>>>(b_theta, b_phi, btp);
    transpose_x_kernel<<<dim3(T_DIM / 32, C_DIM / 32, B_DIM), blk, 0, stream>>>(x, xt);

    // merged theta|phi conv: tp[t][0:1024] = relu(xt . wtp + btp)  M=T,N=1024
    gemm_tn<1><<<dim3(1024 / 128, T_DIM / 128, B_DIM), blk, 0, stream>>>(
        xt, TC, C_DIM, wtp, 0, C_DIM, tp, (size_t)T_DIM * 1024, 1024,
        btp, nullptr, 0, C_DIM);
    // g[c][t] = relu(w_g . xt + b_g[c])   M=C, N=T
    gemm_tn<2><<<dim3(T_DIM / 128, C_DIM / 128, B_DIM), blk, 0, stream>>>(
        wg_h, 0, C_DIM, xt, TC, C_DIM, g, TC, T_DIM, b_g, nullptr, 0, C_DIM);
    // scores[i][j] = theta . phi   (theta = tp cols 0:512, phi = cols 512:1024)
    gemm_tn<0><<<dim3(T_DIM / 128, T_DIM / 128, B_DIM), blk, 0, stream>>>(
        tp, (size_t)T_DIM * 1024, 1024, tp + 512, (size_t)T_DIM * 1024, 1024,
        scores, TT, T_DIM, nullptr, nullptr, 0, C_DIM);
    softmax_f16_kernel<<<dim3(B_DIM * T_DIM), blk, 0, stream>>>(scores);
    // feature[i][c] = attn . g   M=T, N=C, K=T
    gemm_tn<0><<<dim3(C_DIM / 128, T_DIM / 128, B_DIM), blk, 0, stream>>>(
        scores, TT, T_DIM, g, TC, T_DIM, feature, TC, C_DIM, nullptr, nullptr, 0, T_DIM);
    // out[c][t] = relu(w_w . feature + b_w[c]) + x   M=C, N=T
    gemm_tn<3><<<dim3(T_DIM / 128, C_DIM / 128, B_DIM), blk, 0, stream>>>(
        ww_h, 0, C_DIM, feature, TC, C_DIM, out, TC, T_DIM, b_w, x, TC, C_DIM);
}